// Round 5
// baseline (265.969 us; speedup 1.0000x reference)
//
#include <hip/hip_runtime.h>

// SSIM loss, round 5: register-ring strip kernel, 4-field algebraic form,
// float2/pk_fma packing, 5120 waves.
//   fields: x=(p,t) packed, y=((p+t)^2,(p-t)^2) packed
//   blur(pp)+blur(tt) = (A+B)/2,  blur(pt) = (A-B)/4  where (A,B)=blur(y)
// One wave = 54-col x 33-row strip. Peeled 10-row prologue fills the ring;
// main loop = 3 chunks x 11 phases, all ring indices compile-time.

#define SW 54
#define NSTRIP 10            // 10*54 = 540 >= 512
#define H 33
#define NBAND 16             // 16*33 = 528 >= 512
#define NIMG 32
#define NWAVE (NSTRIP * NBAND * NIMG)   // 5120

typedef float f2 __attribute__((ext_vector_type(2)));

__device__ __forceinline__ f2 shfl_f2(f2 v, int src) {
    long long d = __builtin_bit_cast(long long, v);
    d = __shfl(d, src, 64);
    return __builtin_bit_cast(f2, d);
}

__global__ __launch_bounds__(128, 4)
void ssim_main(const float* __restrict__ pred, const float* __restrict__ targ,
               float* __restrict__ acc, unsigned int* __restrict__ cnt,
               float* __restrict__ out) {
    const float W[11] = {
        0.00102840f, 0.00759876f, 0.03600077f, 0.10936070f, 0.21300554f,
        0.26601173f,
        0.21300554f, 0.10936070f, 0.03600077f, 0.00759876f, 0.00102840f};

    const int waveId = blockIdx.x * 2 + (threadIdx.x >> 6);
    const int img   = waveId / (NSTRIP * NBAND);
    const int rem   = waveId - img * (NSTRIP * NBAND);
    const int band  = rem / NSTRIP;
    const int strip = rem - band * NSTRIP;

    const int L = threadIdx.x & 63;
    const int craw = strip * SW - 5 + L;          // raw col this lane loads
    const bool colOK = (unsigned)craw < 512u;
    const int cidx = min(max(craw, 0), 511);
    const bool outCol = (L < SW) & (strip * SW + L < 512);

    const float* __restrict__ pim = pred + (size_t)img * 262144 + cidx;
    const float* __restrict__ tim = targ + (size_t)img * 262144 + cidx;
    const int rb = band * H;                      // first output row

    f2 rx[11], ry[11];                            // hblurred rings (44 regs)
    float lsum = 0.f;

    // ---- one raw row: load, mask, hblur both packed fields ----
#define ROW_HBLUR(IDX, HX, HY)                                          \
    {                                                                   \
        const int rr = rb - 5 + (IDX);                                  \
        const int rrc = min(max(rr, 0), 511);                           \
        float p = pim[rrc << 9];                                        \
        float t = tim[rrc << 9];                                        \
        const bool ok = colOK & ((unsigned)rr < 512u);                  \
        p = ok ? p : 0.f;                                               \
        t = ok ? t : 0.f;                                               \
        f2 xt; xt.x = p; xt.y = t;                                      \
        HX = W[0] * xt;                                                 \
        {   f2 uv; uv.x = p + t; uv.y = p - t;                          \
            HY = W[0] * (uv * uv); }                                    \
        _Pragma("unroll")                                               \
        for (int k = 1; k < 11; ++k) {                                  \
            f2 w = shfl_f2(xt, L + k);                                  \
            HX += W[k] * w;                                             \
            f2 uv; uv.x = w.x + w.y; uv.y = w.x - w.y;                  \
            HY += W[k] * (uv * uv);                                     \
        }                                                               \
    }

    // ---- prologue: raw rows 0..9 fill ring slots 0..9 ----
#pragma unroll
    for (int i = 0; i < 10; ++i) {
        f2 hx, hy;
        ROW_HBLUR(i, hx, hy);
        rx[i] = hx; ry[i] = hy;
    }

    // ---- main: 3 chunks x 11 phases; raw row i = 10 + 11c + ph ----
    for (int c = 0; c < 3; ++c) {
        const int i0 = 10 + c * 11;
        const int ro0 = rb + c * 11;              // output row at ph=0
#pragma unroll
        for (int ph = 0; ph < 11; ++ph) {
            f2 hx, hy;
            ROW_HBLUR(i0 + ph, hx, hy);
            rx[(10 + ph) % 11] = hx;
            ry[(10 + ph) % 11] = hy;

            // vblur from ring (slots (ph+k)%11, compile-time) + ssim
            f2 mu = W[0] * rx[ph % 11];
            f2 ab = W[0] * ry[ph % 11];
#pragma unroll
            for (int k = 1; k < 11; ++k) {
                mu += W[k] * rx[(ph + k) % 11];
                ab += W[k] * ry[(ph + k) % 11];
            }
            const float m1 = mu.x, m2 = mu.y;
            const float m12 = m1 * m2;
            f2 msq = mu * mu;
            const float smsq = msq.x + msq.y;            // m1^2 + m2^2
            const float bpt = (ab.x - ab.y) * 0.25f;     // blur(pt)
            const float bsq = (ab.x + ab.y) * 0.5f;      // blur(pp)+blur(tt)
            const float s12 = bpt - m12;
            const float s1s2 = bsq - smsq;
            const float num = __builtin_fmaf(2.f, m12, 1e-4f) *
                              __builtin_fmaf(2.f, s12, 9e-4f);
            const float den = (smsq + 1e-4f) * (s1s2 + 9e-4f);
            float rc = __builtin_amdgcn_rcpf(den);
            rc = rc * (2.f - den * rc);                  // Newton step
            const bool ok = outCol & ((ro0 + ph) < 512);
            lsum += ok ? num * rc : 0.f;
        }
    }

    // ---- wave reduce -> one atomic per wave; ticket finalize ----
#pragma unroll
    for (int off = 32; off > 0; off >>= 1)
        lsum += __shfl_down(lsum, off, 64);
    if (L == 0) {
        atomicAdd(acc, lsum);
        __threadfence();
        if (atomicAdd(cnt, 1u) == NWAVE - 1) {
            const float s = atomicAdd(acc, 0.f);
            out[0] = 1.0f - s * (1.0f / 8388608.0f);
        }
    }
}

extern "C" void kernel_launch(void* const* d_in, const int* in_sizes, int n_in,
                              void* d_out, int out_size, void* d_ws,
                              size_t ws_size, hipStream_t stream) {
    const float* pred = (const float*)d_in[0];
    const float* targ = (const float*)d_in[1];
    float* acc = (float*)d_ws;
    unsigned int* cnt = (unsigned int*)((char*)d_ws + 4);

    hipMemsetAsync(d_ws, 0, 8, stream);
    ssim_main<<<dim3(NWAVE / 2), dim3(128), 0, stream>>>(pred, targ, acc, cnt,
                                                         (float*)d_out);
    (void)in_sizes; (void)n_in; (void)out_size; (void)ws_size;
}

// Round 6
// 226.399 us; speedup vs baseline: 1.1748x; 1.1748x over previous
//
#include <hip/hip_runtime.h>
#include <hip/hip_bf16.h>

// SSIM loss, round 6: blurs on the matrix cores.
// hblur: D[16 img rows][16 out cols] = A(raw data) x B(const band)
// vblur: D[16 img cols][16 out rows] = A(transposed h ring) x B(same band)
// Per wave: private 16-col stripe x 128 out rows; LDS ring of 64 h-rows
// (transposed, bf16) per field; no barriers, no shuffles.
// bf16 inputs / fp32 accumulate; exact sum(W_bf16)^2 correction.

typedef float  f32x4  __attribute__((ext_vector_type(4)));
typedef short  short8 __attribute__((ext_vector_type(8)));
typedef short  short4v __attribute__((ext_vector_type(4)));
typedef float  float4v __attribute__((ext_vector_type(4)));

#define NWAVE 4096   // 32 stripes x 4 row-quarters x 32 images

__device__ __forceinline__ short bf16s(float x) {
    __hip_bfloat16 h = __float2bfloat16(x);
    return __builtin_bit_cast(short, h);
}
__device__ __forceinline__ float bf16f(float x) {   // value after bf16 RNE
    unsigned u = (unsigned)__builtin_bit_cast(unsigned short,
                                              __float2bfloat16(x)) << 16;
    return __builtin_bit_cast(float, u);
}

__global__ __launch_bounds__(256, 4)
void ssim_main(const float* __restrict__ pred, const float* __restrict__ targ,
               float* __restrict__ acc, unsigned int* __restrict__ cnt,
               float* __restrict__ out) {
    const float W[11] = {
        0.00102840f, 0.00759876f, 0.03600077f, 0.10936070f, 0.21300554f,
        0.26601173f,
        0.21300554f, 0.10936070f, 0.03600077f, 0.00759876f, 0.00102840f};

    // [wave][field][col][ringslot]; stride 72 shorts = 144 B (16B-mult, 2-way banks)
    __shared__ __align__(16) short hring[4][4][16][72];   // 36,864 B

    const int w     = threadIdx.x >> 6;
    const int L     = threadIdx.x & 63;
    const int n     = L & 15;          // out col (hblur) / A col m (vblur)
    const int quad  = L >> 4;
    const int waveId = blockIdx.x * 4 + w;
    const int img    = waveId >> 7;
    const int rem    = waveId & 127;
    const int q      = rem >> 5;       // row quarter
    const int stripe = rem & 31;
    const int c0     = stripe << 4;
    const int s0     = q << 3;         // first out row-tile index (of 8)
    const bool edge  = (stripe == 0) | (stripe == 31);

    const float* __restrict__ pim = pred + (size_t)img * 262144;
    const float* __restrict__ tim = targ + (size_t)img * 262144;

    // exact correction: both blur stages scale by S = sum(bf16(W))
    float S = 0.f;
#pragma unroll
    for (int kk = 0; kk < 11; ++kk) S += bf16f(W[kk]);
    const float c2 = 1.0f / (S * S);

    // const band frag B[k][n] = W[k-n-3], k = quad*8+j, n = lane&15
    short8 bw;
#pragma unroll
    for (int j = 0; j < 8; ++j) {
        const int d = quad * 8 + j - n - 3;
        bw[j] = bf16s((d >= 0 && d <= 10) ? W[d] : 0.f);
    }
    const f32x4 zc = {0.f, 0.f, 0.f, 0.f};

    float lsum = 0.f;

    // ---- hblur one 16-row tile T into the ring (4 fields) ----
    auto hstore = [&](int T) {
        const int wslot = (int)(((unsigned)(T << 4)) & 63u) + quad * 4;
        short4v o[4];
        if ((unsigned)T > 31u) {              // rows outside image -> zeros
#pragma unroll
            for (int f = 0; f < 4; ++f) o[f] = (short4v){0, 0, 0, 0};
        } else {
            const int r  = (T << 4) + n;      // image row, 0..511
            const int cb = c0 - 8 + quad * 8; // first raw col of lane's 8
            float p[8], t[8];
            if (!edge) {
                const float4v* pp = (const float4v*)(pim + r * 512 + cb);
                const float4v* tp = (const float4v*)(tim + r * 512 + cb);
                const float4v p0 = pp[0], p1 = pp[1];
                const float4v t0 = tp[0], t1 = tp[1];
#pragma unroll
                for (int j = 0; j < 4; ++j) {
                    p[j] = p0[j]; p[j + 4] = p1[j];
                    t[j] = t0[j]; t[j + 4] = t1[j];
                }
            } else {
#pragma unroll
                for (int j = 0; j < 8; ++j) {
                    const int col = cb + j;
                    const int cc = min(max(col, 0), 511);
                    const float pv = pim[r * 512 + cc];
                    const float tv = tim[r * 512 + cc];
                    const bool ok = (unsigned)col < 512u;
                    p[j] = ok ? pv : 0.f;
                    t[j] = ok ? tv : 0.f;
                }
            }
            short8 fa[4];
#pragma unroll
            for (int j = 0; j < 8; ++j) {
                const float u = p[j] + t[j], v = p[j] - t[j];
                fa[0][j] = bf16s(p[j]);
                fa[1][j] = bf16s(t[j]);
                fa[2][j] = bf16s(u * u);
                fa[3][j] = bf16s(v * v);
            }
#pragma unroll
            for (int f = 0; f < 4; ++f) {
                const f32x4 d = __builtin_amdgcn_mfma_f32_16x16x32_bf16(
                    fa[f], bw, zc, 0, 0, 0);
                short4v ov;
#pragma unroll
                for (int r2 = 0; r2 < 4; ++r2) ov[r2] = bf16s(d[r2]);
                o[f] = ov;
            }
        }
#pragma unroll
        for (int f = 0; f < 4; ++f)
            *(short4v*)&hring[w][f][n][wslot] = o[f];   // ds_write_b64
    };

    // ---- prologue: ring needs tiles s0-1, s0, s0+1 ----
    hstore(s0 - 1);
    hstore(s0);
    hstore(s0 + 1);

    // ---- 8 steps: vblur+ssim out-tile s, then hblur tile s+2 ----
#pragma unroll 1
    for (int s = s0; s < s0 + 8; ++s) {
        const int rslot0 = (int)(((unsigned)((s << 4) - 8)) & 63u);
        const int chunk  = (rslot0 + quad * 8) & 63;   // 8-aligned, no wrap
        f32x4 dv[4];
#pragma unroll
        for (int f = 0; f < 4; ++f) {
            const short8 af = *(const short8*)&hring[w][f][n][chunk]; // b128
            dv[f] = __builtin_amdgcn_mfma_f32_16x16x32_bf16(af, bw, zc, 0, 0, 0);
        }
#pragma unroll
        for (int r = 0; r < 4; ++r) {
            const float m1 = dv[0][r] * c2, m2 = dv[1][r] * c2;
            const float Av = dv[2][r] * c2, Bv = dv[3][r] * c2;
            const float m12  = m1 * m2;
            const float smsq = m1 * m1 + m2 * m2;
            const float s12  = __builtin_fmaf(0.25f, Av - Bv, -m12);
            const float s1s2 = __builtin_fmaf(0.5f,  Av + Bv, -smsq);
            const float num = __builtin_fmaf(2.f, m12, 1e-4f) *
                              __builtin_fmaf(2.f, s12, 9e-4f);
            const float den = (smsq + 1e-4f) * (s1s2 + 9e-4f);
            float rc = __builtin_amdgcn_rcpf(den);
            rc = rc * (2.f - den * rc);                 // Newton step
            lsum = __builtin_fmaf(num, rc, lsum);
        }
        if (s != s0 + 7) hstore(s + 2);
    }

    // ---- wave reduce -> one atomic per wave; ticket finalize ----
#pragma unroll
    for (int off = 32; off > 0; off >>= 1)
        lsum += __shfl_down(lsum, off, 64);
    if (L == 0) {
        atomicAdd(acc, lsum);
        __threadfence();
        if (atomicAdd(cnt, 1u) == NWAVE - 1) {
            const float sfin = atomicAdd(acc, 0.f);
            out[0] = 1.0f - sfin * (1.0f / 8388608.0f);
        }
    }
}

extern "C" void kernel_launch(void* const* d_in, const int* in_sizes, int n_in,
                              void* d_out, int out_size, void* d_ws,
                              size_t ws_size, hipStream_t stream) {
    const float* pred = (const float*)d_in[0];
    const float* targ = (const float*)d_in[1];
    float* acc = (float*)d_ws;
    unsigned int* cnt = (unsigned int*)((char*)d_ws + 4);

    hipMemsetAsync(d_ws, 0, 8, stream);
    ssim_main<<<dim3(NWAVE / 4), dim3(256), 0, stream>>>(pred, targ, acc, cnt,
                                                         (float*)d_out);
    (void)in_sizes; (void)n_in; (void)out_size; (void)ws_size;
}

// Round 7
// 163.170 us; speedup vs baseline: 1.6300x; 1.3875x over previous
//
#include <hip/hip_runtime.h>
#include <hip/hip_bf16.h>

// SSIM loss, round 7: round-6 MFMA blur structure + hierarchical reduction
// (the single-address atomic tail was ~150 us of round 6's 165) + pipelined
// global loads (hload regs -> vblur covers latency -> hproc).
// hblur: D[16 rows][16 cols] = A(raw) x B(const band W[k-n-3])
// vblur: D[16 cols][16 rows] = A(transposed h ring from LDS) x same B
// Per wave: private 16-col stripe x 128 out rows, no barriers in compute.

typedef float  f32x4  __attribute__((ext_vector_type(4)));
typedef short  short8 __attribute__((ext_vector_type(8)));
typedef short  short4v __attribute__((ext_vector_type(4)));
typedef float  float4v __attribute__((ext_vector_type(4)));

#define NBLOCK 1024   // x4 waves = 4096 waves; whole grid resident (4 blk/CU)

__device__ __forceinline__ short bf16s(float x) {
    __hip_bfloat16 h = __float2bfloat16(x);
    return __builtin_bit_cast(short, h);
}
__device__ __forceinline__ float bf16f(float x) {
    unsigned u = (unsigned)__builtin_bit_cast(unsigned short,
                                              __float2bfloat16(x)) << 16;
    return __builtin_bit_cast(float, u);
}

__global__ __launch_bounds__(256, 4)
void ssim_main(const float* __restrict__ pred, const float* __restrict__ targ,
               float* __restrict__ slotSum, unsigned int* __restrict__ grpCnt,
               unsigned int* __restrict__ finalCnt, float* __restrict__ out) {
    const float W[11] = {
        0.00102840f, 0.00759876f, 0.03600077f, 0.10936070f, 0.21300554f,
        0.26601173f,
        0.21300554f, 0.10936070f, 0.03600077f, 0.00759876f, 0.00102840f};

    __shared__ __align__(16) short hring[4][4][16][72];   // 36,864 B
    __shared__ float wsum[4];

    const int w     = threadIdx.x >> 6;
    const int L     = threadIdx.x & 63;
    const int n     = L & 15;
    const int quad  = L >> 4;
    const int waveId = blockIdx.x * 4 + w;
    const int img    = waveId >> 7;
    const int rem    = waveId & 127;
    const int q      = rem >> 5;
    const int stripe = rem & 31;
    const int c0     = stripe << 4;
    const int s0     = q << 3;
    const bool edge  = (stripe == 0) | (stripe == 31);

    const float* __restrict__ pim = pred + (size_t)img * 262144;
    const float* __restrict__ tim = targ + (size_t)img * 262144;

    float S = 0.f;
#pragma unroll
    for (int kk = 0; kk < 11; ++kk) S += bf16f(W[kk]);
    const float c2 = 1.0f / (S * S);

    short8 bw;
#pragma unroll
    for (int j = 0; j < 8; ++j) {
        const int d = quad * 8 + j - n - 3;
        bw[j] = bf16s((d >= 0 && d <= 10) ? W[d] : 0.f);
    }
    const f32x4 zc = {0.f, 0.f, 0.f, 0.f};

    float lsum = 0.f;
    float P[8], T[8];                  // pending raw tile (pipeline buffer)

    // ---- issue global loads for tile Tt into P/T ----
    auto hload = [&](int Tt) {
        if ((unsigned)Tt > 31u) {
#pragma unroll
            for (int j = 0; j < 8; ++j) { P[j] = 0.f; T[j] = 0.f; }
            return;
        }
        const int r  = (Tt << 4) + n;
        const int cb = c0 - 8 + quad * 8;
        if (!edge) {
            const float4v* pp = (const float4v*)(pim + r * 512 + cb);
            const float4v* tp = (const float4v*)(tim + r * 512 + cb);
            const float4v p0 = pp[0], p1 = pp[1];
            const float4v t0 = tp[0], t1 = tp[1];
#pragma unroll
            for (int j = 0; j < 4; ++j) {
                P[j] = p0[j]; P[j + 4] = p1[j];
                T[j] = t0[j]; T[j + 4] = t1[j];
            }
        } else {
#pragma unroll
            for (int j = 0; j < 8; ++j) {
                const int col = cb + j;
                const int cc = min(max(col, 0), 511);
                const float pv = pim[r * 512 + cc];
                const float tv = tim[r * 512 + cc];
                const bool ok = (unsigned)col < 512u;
                P[j] = ok ? pv : 0.f;
                T[j] = ok ? tv : 0.f;
            }
        }
    };

    // ---- cvt + hblur MFMA + ring store for pending tile ----
    auto hproc = [&](int Tt) {
        const int wslot = (int)(((unsigned)(Tt << 4)) & 63u) + quad * 4;
        short4v o[4];
        if ((unsigned)Tt > 31u) {
#pragma unroll
            for (int f = 0; f < 4; ++f) o[f] = (short4v){0, 0, 0, 0};
        } else {
            short8 fa[4];
#pragma unroll
            for (int j = 0; j < 8; ++j) {
                const float u = P[j] + T[j], v = P[j] - T[j];
                fa[0][j] = bf16s(P[j]);
                fa[1][j] = bf16s(T[j]);
                fa[2][j] = bf16s(u * u);
                fa[3][j] = bf16s(v * v);
            }
#pragma unroll
            for (int f = 0; f < 4; ++f) {
                const f32x4 d = __builtin_amdgcn_mfma_f32_16x16x32_bf16(
                    fa[f], bw, zc, 0, 0, 0);
                short4v ov;
#pragma unroll
                for (int r2 = 0; r2 < 4; ++r2) ov[r2] = bf16s(d[r2]);
                o[f] = ov;
            }
        }
#pragma unroll
        for (int f = 0; f < 4; ++f)
            *(short4v*)&hring[w][f][n][wslot] = o[f];
    };

    // ---- prologue: tiles s0-1, s0, s0+1 ----
    hload(s0 - 1); hproc(s0 - 1);
    hload(s0);     hproc(s0);
    hload(s0 + 1); hproc(s0 + 1);

    // ---- 8 steps: issue loads(s+2) -> vblur+ssim(s) -> hproc(s+2) ----
#pragma unroll 1
    for (int s = s0; s < s0 + 8; ++s) {
        if (s < s0 + 7) hload(s + 2);           // fire loads early

        const int rslot0 = (int)(((unsigned)((s << 4) - 8)) & 63u);
        const int chunk  = (rslot0 + quad * 8) & 63;
        f32x4 dv[4];
#pragma unroll
        for (int f = 0; f < 4; ++f) {
            const short8 af = *(const short8*)&hring[w][f][n][chunk];
            dv[f] = __builtin_amdgcn_mfma_f32_16x16x32_bf16(af, bw, zc, 0, 0, 0);
        }
#pragma unroll
        for (int r = 0; r < 4; ++r) {
            const float m1 = dv[0][r] * c2, m2 = dv[1][r] * c2;
            const float Av = dv[2][r] * c2, Bv = dv[3][r] * c2;
            const float m12  = m1 * m2;
            const float smsq = m1 * m1 + m2 * m2;
            const float s12  = __builtin_fmaf(0.25f, Av - Bv, -m12);
            const float s1s2 = __builtin_fmaf(0.5f,  Av + Bv, -smsq);
            const float num = __builtin_fmaf(2.f, m12, 1e-4f) *
                              __builtin_fmaf(2.f, s12, 9e-4f);
            const float den = (smsq + 1e-4f) * (s1s2 + 9e-4f);
            float rc = __builtin_amdgcn_rcpf(den);
            rc = rc * (2.f - den * rc);
            lsum = __builtin_fmaf(num, rc, lsum);
        }
        if (s < s0 + 7) hproc(s + 2);           // waits vmcnt here, not above
    }

    // ---- hierarchical reduce ----
#pragma unroll
    for (int off = 32; off > 0; off >>= 1)
        lsum += __shfl_down(lsum, off, 64);
    if (L == 0) wsum[w] = lsum;
    __syncthreads();
    if (threadIdx.x == 0) {
        const float bs = wsum[0] + wsum[1] + wsum[2] + wsum[3];
        const int g = blockIdx.x & 63;           // 64 groups x 16 blocks
        atomicAdd(&slotSum[g * 16], bs);         // slots 64 B apart
        __threadfence();
        if (atomicAdd(&grpCnt[g * 16], 1u) == 15u) {
            __threadfence();
            if (atomicAdd(finalCnt, 1u) == 63u) {
                float s = 0.f;
#pragma unroll
                for (int i = 0; i < 64; ++i)
                    s += atomicAdd(&slotSum[i * 16], 0.f);  // coherent reads
                out[0] = 1.0f - s * (1.0f / 8388608.0f);
            }
        }
    }
}

extern "C" void kernel_launch(void* const* d_in, const int* in_sizes, int n_in,
                              void* d_out, int out_size, void* d_ws,
                              size_t ws_size, hipStream_t stream) {
    const float* pred = (const float*)d_in[0];
    const float* targ = (const float*)d_in[1];
    // ws layout: [0,4096) slotSum[64] @64B stride; [4096,8192) grpCnt[64]
    //            @64B stride; [8192,8196) finalCnt
    float* slotSum = (float*)d_ws;
    unsigned int* grpCnt = (unsigned int*)((char*)d_ws + 4096);
    unsigned int* finalCnt = (unsigned int*)((char*)d_ws + 8192);

    hipMemsetAsync(d_ws, 0, 8196, stream);
    ssim_main<<<dim3(NBLOCK), dim3(256), 0, stream>>>(pred, targ, slotSum,
                                                      grpCnt, finalCnt,
                                                      (float*)d_out);
    (void)in_sizes; (void)n_in; (void)out_size; (void)ws_size;
}